// Round 18
// baseline (266.872 us; speedup 1.0000x reference)
//
#include <hip/hip_runtime.h>

// DepthDeformConvPack on MI355X — round 22: split-bf16 offset GEMM.
// r21 post-mortem (FAILED absmax 0.02539 vs 0.025 — 1.6% over): the MFMA
// offset-GEMM structure is CORRECT (an indexing bug gives 0.36-468, not
// 0.0254); single-bf16 quantization of inputs+weights leaked ~0.018 into
// the output (~3x the sqrt(K) estimate — systematic). Fix: hi/lo split
// bf16 on BOTH operands: v = hi + lo (hi=bf16(v), lo=bf16(v-hi), residual
// <= 2^-18 rel); W*B ~= Whi*Bhi + Whi*Blo + Wlo*Bhi (drop Wlo*Blo).
// Offset error -> ~1e-5 px => absmax back to baseline 0.0078.
// Cost: 9 MFMAs/step (vs 3), Bs doubled (26.6KB LDS), wo hi/lo pair in
// k_prep. Everything else byte-identical to r21 (D2 = proven r19/r20).
// Predict: PASS at 0.0078; k_offset_gemm 20-30us; total ~160-185us.

typedef __bf16 bf16x8 __attribute__((ext_vector_type(8)));
typedef float f32x4 __attribute__((ext_vector_type(4)));
typedef float float2_u __attribute__((ext_vector_type(2), aligned(4)));

__device__ __forceinline__ unsigned short f2bf(float f) {
  unsigned b = __float_as_uint(f);
  return (unsigned short)((b + 0x7fffu + ((b >> 16) & 1u)) >> 16);
}
__device__ __forceinline__ float bf2f(unsigned short h) {
  return __uint_as_float((unsigned)h << 16);
}

// ---------------------------------------------------------------------------
// P0: weight preps. grid 2304 x 256.
//   wbf[i] = bf16(weight[i])                                  (589824)
//   wo_hi/wo_lo[co*2880+k] = hi/lo split of off_w (co<18 else 0) (92160 ea)
// ---------------------------------------------------------------------------
__global__ __launch_bounds__(256) void k_prep(
    const float* __restrict__ w, const float* __restrict__ off_w,
    unsigned short* __restrict__ wbf, unsigned short* __restrict__ wo_hi,
    unsigned short* __restrict__ wo_lo)
{
  const int i = blockIdx.x * 256 + threadIdx.x;   // 0..589823
  wbf[i] = f2bf(w[i]);
  if (i < 92160) {
    const int co = i / 2880;
    const float wv = (co < 18) ? off_w[i] : 0.f;
    const unsigned short hi = f2bf(wv);
    wo_hi[i] = hi;
    wo_lo[i] = f2bf(wv - bf2f(hi));
  }
}

// ---------------------------------------------------------------------------
// D1: offset conv as split-bf16 MFMA GEMM. 256 blocks (n,ho) x 512 thr.
// Wave wv -> C-tile (mt = wv>>2, nt = wv&3). K = 2880 = 30 steps x 96.
// acc += Whi*Bhi + Whi*Blo + Wlo*Bhi  (per 32-k chunk).
// ---------------------------------------------------------------------------
__global__ __launch_bounds__(512) void k_offset_gemm(
    const float* __restrict__ x, const float* __restrict__ depth,
    const unsigned short* __restrict__ wo_hi,
    const unsigned short* __restrict__ wo_lo,
    const float* __restrict__ off_b, float* __restrict__ offs)
{
  __shared__ __align__(16) unsigned short BsH[64][104];  // 13312 B
  __shared__ __align__(16) unsigned short BsL[64][104];  // 13312 B

  const int tid  = threadIdx.x;
  const int n    = blockIdx.x >> 6, ho = blockIdx.x & 63;
  const int lane = tid & 63;
  const int wv   = tid >> 6;        // 0..7
  const int mt   = wv >> 2;         // 0..1  co-tile
  const int nt   = wv & 3;          // 0..3  px-tile
  const int mrow = lane & 15;
  const int koct = lane >> 4;       // 0..3
  const int px   = lane;            // build role: one px column per lane

  // cooperative build for K-chunk [kc, kc+96): wave wv fills k-lanes
  // [kc + wv*12, +12) for its px column, hi+lo split.
  auto build = [&](int kc) {
    __align__(8) unsigned short vh[12], vl[12];
#pragma unroll
    for (int j = 0; j < 12; ++j) {
      const int k  = kc + wv * 12 + j;
      const int c  = (int)(((unsigned)k * 7282u) >> 16);   // k/9 (k<2880 ok)
      const int tap = k - 9 * c;
      const int ky = tap / 3, kx = tap - 3 * ky;
      const int yr = ho - 1 + ky;
      const int xc = px - 1 + kx;
      const float* p = (c < 256) ? (x + (((n << 8) + c) << 12))
                                 : (depth + (((n << 6) + (c - 256)) << 12));
      const int yrc = min(max(yr, 0), 63), xcc = min(max(xc, 0), 63);
      const float f = (((unsigned)yr < 64u) && ((unsigned)xc < 64u)) ? 1.f : 0.f;
      const float val = p[(yrc << 6) + xcc] * f;
      const unsigned short hi = f2bf(val);
      vh[j] = hi;
      vl[j] = f2bf(val - bf2f(hi));
    }
    *(int2*)&BsH[px][wv * 12]     = *(const int2*)&vh[0];
    *(int2*)&BsH[px][wv * 12 + 4] = *(const int2*)&vh[4];
    *(int2*)&BsH[px][wv * 12 + 8] = *(const int2*)&vh[8];
    *(int2*)&BsL[px][wv * 12]     = *(const int2*)&vl[0];
    *(int2*)&BsL[px][wv * 12 + 4] = *(const int2*)&vl[4];
    *(int2*)&BsL[px][wv * 12 + 8] = *(const int2*)&vl[8];
  };

  f32x4 acc;
#pragma unroll
  for (int r = 0; r < 4; ++r) acc[r] = 0.f;

  const int arow = ((mt << 4) + mrow) * 2880;
  const unsigned short* ah = wo_hi + arow;
  const unsigned short* al = wo_lo + arow;
  const int brow = (nt << 4) + mrow;

  for (int st = 0; st < 30; ++st) {
    const int kc = st * 96;
    // A-frags issued first (L2-hot, in flight during build)
    bf16x8 afh[3], afl[3];
#pragma unroll
    for (int q = 0; q < 3; ++q) {
      afh[q] = *(const bf16x8*)(ah + kc + q * 32 + (koct << 3));
      afl[q] = *(const bf16x8*)(al + kc + q * 32 + (koct << 3));
    }

    build(kc);
    __syncthreads();            // Bs complete

#pragma unroll
    for (int q = 0; q < 3; ++q) {
      const bf16x8 bh = *(const bf16x8*)&BsH[brow][q * 32 + (koct << 3)];
      const bf16x8 bl = *(const bf16x8*)&BsL[brow][q * 32 + (koct << 3)];
      acc = __builtin_amdgcn_mfma_f32_16x16x32_bf16(afh[q], bh, acc, 0, 0, 0);
      acc = __builtin_amdgcn_mfma_f32_16x16x32_bf16(afh[q], bl, acc, 0, 0, 0);
      acc = __builtin_amdgcn_mfma_f32_16x16x32_bf16(afl[q], bh, acc, 0, 0, 0);
    }
    __syncthreads();            // Bs free for next build
  }

  // epilogue (K3-proven C/D layout): col=lane&15 (px), row=(lane>>4)*4+r (co)
#pragma unroll
  for (int r = 0; r < 4; ++r) {
    const int co = (mt << 4) + ((lane >> 4) << 2) + r;
    if (co < 18) {
      const int wo = (nt << 4) + (lane & 15);
      offs[((n * 18 + co) << 12) + (ho << 6) + wo] = acc[r] + off_b[co];
    }
  }
}

// ---------------------------------------------------------------------------
// D2: fused mask deform conv (K2) + main modulated deform conv GEMM (K3).
// Block = (n,ho) via XCD swizzle, 512 thr = 8 waves, grid 256.  (= r19/r20)
// LDS pool layout (101376 B):
//   [0      .. 78336) strip   9 x 8704
//   [78336  .. 87552) Bs      64 x 72 u16     \
//   [87552  .. 96768) pwT     9 x 64 float4    > aliased by red[8][9][64]
//   [96768  .. 99072) piT     9 x 64 int      /  (18432 B, phase-M only)
//   [99072  ..101376) mskL    9 x 64 float
// ---------------------------------------------------------------------------
__device__ __forceinline__ void stage_channel_row(const float* src, char* dstb,
                                                  int lane) {
  // 32 rows x 256B; each size-4 call writes one row (64 lanes x 4B, linear).
  const char* s = (const char*)src + lane * 4;
#pragma unroll
  for (int j = 0; j < 32; ++j)
    __builtin_amdgcn_global_load_lds(
        (const __attribute__((address_space(1))) void*)(s + j * 256),
        (__attribute__((address_space(3))) void*)(dstb + j * 272), 4, 0, 0);
}

__global__ __launch_bounds__(512, 2) void k_fused_gemm(
    const float* __restrict__ x, const float* __restrict__ depth,
    const float* __restrict__ offs, const float* __restrict__ mask_w,
    const float* __restrict__ mask_b, const unsigned short* __restrict__ wbf,
    const float* __restrict__ bias, float* __restrict__ out)
{
  __shared__ __align__(16) char pool[101376];
  char* stripc = pool;
  unsigned short (*Bs)[72]  = (unsigned short (*)[72])(pool + 78336);
  float4 (*pwT)[64]         = (float4 (*)[64])(pool + 87552);
  int (*piT)[64]            = (int (*)[64])(pool + 96768);
  float (*mskL)[64]         = (float (*)[64])(pool + 99072);
  float (*red)[9][64]       = (float (*)[9][64])(pool + 78336);  // phase-M alias

  const int tid = threadIdx.x;
  // XCD swizzle: b&7 = XCD; each XCD owns a 32-row strip of one batch.
  const int b    = blockIdx.x;            // 256 blocks
  const int xcd  = b & 7, bslot = b >> 3; // bslot 0..31
  const int n    = xcd >> 1;
  const int ho   = ((xcd & 1) << 5) + bslot;      // 0..63
  const int pxb  = ho << 6;                       // px base within batch
  const int ylo  = min(max(ho - 15, 0), 32);      // strip rows [ylo, ylo+32)

  const int pxl  = tid & 63;        // px within row (= lane)
  const int oct  = tid >> 6;        // wave id; k-octet of 8
  const int lane = tid & 63;
  const int mrow = lane & 15;
  const int koct = lane >> 4;       // 0..3 -> k-subgroup of 8
  const float* xn = x + ((long)(n << 8) << 12);

  // --- prologue: stage channels 0..7 (window of iter 0), one per wave.
  stage_channel_row(xn + (oct << 12) + (ylo << 6), stripc + oct * 8704, lane);
  int c_staged = 8;

  // =============== Phase M: mask deform conv for this (n,ho) row ===========
  {
    const int wo = lane;
    int ia[9], ib[9];
    float w0[9], w1[9], w2c[9], w3[9];
    const float* op = offs + ((n * 18) << 12) + (ho << 6) + wo;
#pragma unroll
    for (int k = 0; k < 9; ++k) {
      const float dy = op[(2 * k) << 12];
      const float dx = op[(2 * k + 1) << 12];
      const float yy = (float)(ho - 1 + k / 3) + dy;
      const float xx = (float)(wo - 1 + k % 3) + dx;
      const float y0f = floorf(yy), x0f = floorf(xx);
      const float ly = yy - y0f, lx = xx - x0f;
      const int y0 = (int)y0f, x0 = (int)x0f;
      const int y0c = min(max(y0, 0), 63);
      const int y1c = min(max(y0 + 1, 0), 63);
      const float fy0 = (y0 >= 0 && y0 < 64) ? 1.f : 0.f;
      const float fy1 = (y0 >= -1 && y0 < 63) ? 1.f : 0.f;
      const int x0c = min(max(x0, 0), 63);
      const int x1c = min(max(x0 + 1, 0), 63);
      const int bx  = min(max(x0, 0), 62);
      const float vx0 = (x0 >= 0 && x0 < 64) ? 1.f : 0.f;
      const float vx1 = (x0 >= -1 && x0 < 63) ? 1.f : 0.f;
      const float wl = (1.f - lx) * vx0 * ((x0c == bx) ? 1.f : 0.f)
                     + lx * vx1 * ((x1c == bx) ? 1.f : 0.f);
      const float wr = (1.f - lx) * vx0 * ((x0c == bx + 1) ? 1.f : 0.f)
                     + lx * vx1 * ((x1c == bx + 1) ? 1.f : 0.f);
      const float a0 = (1.f - ly) * fy0;
      const float a1 = ly * fy1;
      ia[k] = ((y0c << 6) + bx) << 2;
      ib[k] = ((y1c << 6) + bx) << 2;
      w0[k] = wl * a0;  w1[k] = wr * a0;
      w2c[k] = wl * a1; w3[k] = wr * a1;
    }

    float acc2[9];
#pragma unroll
    for (int i = 0; i < 9; ++i) acc2[i] = 0.f;

    const int cbase = __builtin_amdgcn_readfirstlane(oct * 8);
    for (int cc = 0; cc < 8; ++cc) {
      const int c = cbase + cc;
      const char* p = (const char*)(depth + (((n << 6) + c) << 12));
      float val[9];
#pragma unroll
      for (int k = 0; k < 9; ++k) {
        const float2_u A = *(const float2_u*)(p + ia[k]);
        const float2_u B = *(const float2_u*)(p + ib[k]);
        val[k] = A.x * w0[k] + A.y * w1[k] + B.x * w2c[k] + B.y * w3[k];
      }
      const float* wp = mask_w + c * 9;
#pragma unroll
      for (int co = 0; co < 9; ++co) {
#pragma unroll
        for (int k = 0; k < 9; ++k) acc2[co] += val[k] * wp[co * 576 + k];
      }
    }
#pragma unroll
    for (int co = 0; co < 9; ++co) red[oct][co][lane] = acc2[co];
  }
  __syncthreads();   // red complete (also drains prologue staging vmcnt)

  for (int o = tid; o < 576; o += 512) {
    const int co = o >> 6, wo = o & 63;
    float s = mask_b[co];
#pragma unroll
    for (int wv = 0; wv < 8; ++wv) s += red[wv][co][wo];
    mskL[co][wo] = 1.f / (1.f + expf(-s));
  }
  __syncthreads();   // mskL ready; red dead -> Bs/pwT/piT region free

  // =============== Phase P: sampling params into LDS tables ================
  for (int e = tid; e < 576; e += 512) {
    const int tap = e >> 6, pl = e & 63;
    const int wo = pl;
    const float dy = offs[((n * 18 + 2 * tap) << 12) + pxb + pl];
    const float dx = offs[((n * 18 + 2 * tap + 1) << 12) + pxb + pl];
    const float m  = mskL[tap][pl];
    const float yy = (float)(ho - 1 + tap / 3) + dy;
    const float xx = (float)(wo - 1 + tap % 3) + dx;
    const float y0f = floorf(yy), x0f = floorf(xx);
    const float ly = yy - y0f, lx = xx - x0f;
    const int y0 = (int)y0f, x0 = (int)x0f;
    const int y0c = min(max(y0, 0), 63);
    const int y1c = min(max(y0 + 1, 0), 63);
    const float fy0 = (y0 >= 0 && y0 < 64) ? 1.f : 0.f;
    const float fy1 = (y0 >= -1 && y0 < 63) ? 1.f : 0.f;
    const int x0c = min(max(x0, 0), 63);
    const int x1c = min(max(x0 + 1, 0), 63);
    const int bx  = min(max(x0, 0), 62);
    const float vx0 = (x0 >= 0 && x0 < 64) ? 1.f : 0.f;
    const float vx1 = (x0 >= -1 && x0 < 63) ? 1.f : 0.f;
    const float wl = (1.f - lx) * vx0 * ((x0c == bx) ? 1.f : 0.f)
                   + lx * vx1 * ((x1c == bx) ? 1.f : 0.f);
    const float wr = (1.f - lx) * vx0 * ((x0c == bx + 1) ? 1.f : 0.f)
                   + lx * vx1 * ((x1c == bx + 1) ? 1.f : 0.f);
    const float a0 = (1.f - ly) * fy0 * m;
    const float a1 = ly * fy1 * m;
    pwT[tap][pl] = make_float4(wl * a0, wr * a0, wl * a1, wr * a1);
    // strip-relative byte addrs (row stride 272B) + bad flag
    const int ry0 = y0c - ylo, ry1 = y1c - ylo;
    const int ry0c = min(max(ry0, 0), 31), ry1c = min(max(ry1, 0), 31);
    const int bad = ((ry0 != ry0c) || (ry1 != ry1c)) ? 1 : 0;
    const int ad0 = ry0c * 272 + (bx << 2);      // <= 8680 < 16384
    const int ad1 = ry1c * 272 + (bx << 2);
    piT[tap][pl] = ad0 | (ad1 << 14) | (bad << 28);
  }
  __syncthreads();   // params + prologue strip visible

  // --- gather: one k-octet (8 k) per lane into Bs; params from LDS tables.
  auto gather = [&](int ic) {
    const int k0 = (ic << 6) + (oct << 3);
    const int c0 = (int)(((unsigned)k0 * 7282u) >> 16);    // k0/9
    int tap = k0 - 9 * c0;
    const int s9 = (int)(((unsigned)c0 * 7282u) >> 16);    // c0/9
    int soff = (c0 - 9 * s9) * 8704;                       // slot byte offset

    __align__(16) unsigned short v[8];
    unsigned badm = 0;
#pragma unroll
    for (int j = 0; j < 8; ++j) {
      const int pk  = piT[tap][pxl];              // ds_read_b32
      const float4 w = pwT[tap][pxl];             // ds_read_b128
      const float2_u A = *(const float2_u*)(stripc + soff + (pk & 16383));
      const float2_u B = *(const float2_u*)(stripc + soff + ((pk >> 14) & 16383));
      v[j] = f2bf(A.x * w.x + A.y * w.y + B.x * w.z + B.y * w.w);
      badm |= ((unsigned)pk >> 28) << j;          // bit28 = bad
      if (++tap == 9) {
        tap = 0;
        soff += 8704; if (soff == 9 * 8704) soff = 0;
      }
    }

    if (__builtin_expect(badm != 0, 0)) {         // ~10 events per launch
#pragma unroll
      for (int j = 0; j < 8; ++j) if (badm & (1u << j)) {
        const int k = k0 + j;
        const int c = (int)(((unsigned)k * 7282u) >> 16);
        const int tp = k - 9 * c;
        // full recompute from global (identical math to phase P)
        const float dy = offs[((n * 18 + 2 * tp) << 12) + pxb + pxl];
        const float dx = offs[((n * 18 + 2 * tp + 1) << 12) + pxb + pxl];
        const float m  = mskL[tp][pxl];
        const float yy = (float)(ho - 1 + tp / 3) + dy;
        const float xx = (float)(pxl - 1 + tp % 3) + dx;
        const float y0f = floorf(yy), x0f = floorf(xx);
        const float ly = yy - y0f, lx = xx - x0f;
        const int y0 = (int)y0f, x0 = (int)x0f;
        const int y0c = min(max(y0, 0), 63);
        const int y1c = min(max(y0 + 1, 0), 63);
        const float fy0 = (y0 >= 0 && y0 < 64) ? 1.f : 0.f;
        const float fy1 = (y0 >= -1 && y0 < 63) ? 1.f : 0.f;
        const int x0c = min(max(x0, 0), 63);
        const int x1c = min(max(x0 + 1, 0), 63);
        const int bx  = min(max(x0, 0), 62);
        const float vx0 = (x0 >= 0 && x0 < 64) ? 1.f : 0.f;
        const float vx1 = (x0 >= -1 && x0 < 63) ? 1.f : 0.f;
        const float wl = (1.f - lx) * vx0 * ((x0c == bx) ? 1.f : 0.f)
                       + lx * vx1 * ((x1c == bx) ? 1.f : 0.f);
        const float wr = (1.f - lx) * vx0 * ((x0c == bx + 1) ? 1.f : 0.f)
                       + lx * vx1 * ((x1c == bx + 1) ? 1.f : 0.f);
        const float a0 = (1.f - ly) * fy0 * m;
        const float a1 = ly * fy1 * m;
        const char* pg = (const char*)xn + ((long)c << 14);
        const float2_u Ag = *(const float2_u*)(pg + (((y0c << 6) + bx) << 2));
        const float2_u Bg = *(const float2_u*)(pg + (((y1c << 6) + bx) << 2));
        v[j] = f2bf(Ag.x * (wl * a0) + Ag.y * (wr * a0) +
                    Bg.x * (wl * a1) + Bg.y * (wr * a1));
      }
    }
    *(int4*)&Bs[pxl][oct << 3] = *(const int4*)v;
  };

  // A-fragment prefetch registers for iter 0
  bf16x8 afc[2][2];
#pragma unroll
  for (int mt = 0; mt < 2; ++mt)
#pragma unroll
    for (int ks = 0; ks < 2; ++ks) {
      const int row = (oct << 5) + (mt << 4) + mrow;
      const int col = (ks << 5) + (koct << 3);
      afc[mt][ks] = *(const bf16x8*)(wbf + row * 2304 + col);
    }

  gather(0);
  __syncthreads();

  f32x4 acc[2][4];
#pragma unroll
  for (int mt = 0; mt < 2; ++mt)
#pragma unroll
    for (int nt = 0; nt < 4; ++nt)
#pragma unroll
      for (int r = 0; r < 4; ++r) acc[mt][nt][r] = 0.f;

  for (int ic = 0; ic < 36; ++ic) {
    // stage next window (overlaps MFMA; drained at barrier) + af prefetch
    if (ic < 35) {
      const int c_end = (64 * ic + 127) / 9;          // c_hi(ic+1) <= 255
      const int cw = c_staged + oct;
      if (cw <= c_end) {
        const int slt = cw - 9 * (int)(((unsigned)cw * 7282u) >> 16);
        stage_channel_row(xn + (cw << 12) + (ylo << 6),
                          stripc + slt * 8704, lane);
      }
      c_staged = c_end + 1;
    }

    bf16x8 afn[2][2];
    if (ic < 35) {
      const int kc = (ic + 1) << 6;
#pragma unroll
      for (int mt = 0; mt < 2; ++mt)
#pragma unroll
        for (int ks = 0; ks < 2; ++ks) {
          const int row = (oct << 5) + (mt << 4) + mrow;
          const int col = kc + (ks << 5) + (koct << 3);
          afn[mt][ks] = *(const bf16x8*)(wbf + row * 2304 + col);
        }
    }

#pragma unroll
    for (int ks = 0; ks < 2; ++ks)
#pragma unroll
      for (int nt = 0; nt < 4; ++nt) {
        const bf16x8 bfr =
            *(const bf16x8*)&Bs[(nt << 4) + mrow][(ks << 5) + (koct << 3)];
        acc[0][nt] = __builtin_amdgcn_mfma_f32_16x16x32_bf16(afc[0][ks], bfr,
                                                             acc[0][nt], 0, 0, 0);
        acc[1][nt] = __builtin_amdgcn_mfma_f32_16x16x32_bf16(afc[1][ks], bfr,
                                                             acc[1][nt], 0, 0, 0);
      }

    __syncthreads();           // drains stage; Bs free for rewrite
    if (ic < 35) gather(ic + 1);
    __syncthreads();           // Bs ready for next MFMA; strip safe to restage

#pragma unroll
    for (int mt = 0; mt < 2; ++mt)
#pragma unroll
      for (int ks = 0; ks < 2; ++ks) afc[mt][ks] = afn[mt][ks];
  }

  // epilogue: C/D layout col=lane&15 (px), row=(lane>>4)*4+r (co)
#pragma unroll
  for (int mt = 0; mt < 2; ++mt)
#pragma unroll
    for (int nt = 0; nt < 4; ++nt)
#pragma unroll
      for (int r = 0; r < 4; ++r) {
        const int co = (oct << 5) + (mt << 4) + ((lane >> 4) << 2) + r;
        const int pxg = pxb + (nt << 4) + (lane & 15);
        out[(((n << 8) + co) << 12) + pxg] = acc[mt][nt][r] + bias[co];
      }
}

// ---------------------------------------------------------------------------
extern "C" void kernel_launch(void* const* d_in, const int* in_sizes, int n_in,
                              void* d_out, int out_size, void* d_ws, size_t ws_size,
                              hipStream_t stream) {
  const float* x      = (const float*)d_in[0];
  const float* depth  = (const float*)d_in[1];
  const float* weight = (const float*)d_in[2];
  const float* bias   = (const float*)d_in[3];
  const float* off_w  = (const float*)d_in[4];
  const float* off_b  = (const float*)d_in[5];
  const float* mask_w = (const float*)d_in[6];
  const float* mask_b = (const float*)d_in[7];
  float* out = (float*)d_out;

  float* offs = (float*)d_ws;                              // 294912 f
  unsigned short* wbf = (unsigned short*)(offs + 294912);  // 589824 u16
  unsigned short* wo_hi = wbf + 589824;                    // 92160 u16
  unsigned short* wo_lo = wo_hi + 92160;                   // 92160 u16

  k_prep<<<2304, 256, 0, stream>>>(weight, off_w, wbf, wo_hi, wo_lo);
  k_offset_gemm<<<256, 512, 0, stream>>>(x, depth, wo_hi, wo_lo, off_b, offs);
  k_fused_gemm<<<256, 512, 0, stream>>>(x, depth, offs, mask_w, mask_b,
                                        wbf, bias, out);
}

// Round 19
// 235.101 us; speedup vs baseline: 1.1351x; 1.1351x over previous
//
#include <hip/hip_runtime.h>

// DepthDeformConvPack on MI355X — round 23: restore r19 (best, 235.6us) +
// XCD swizzle on D1. r22 post-mortem: split-bf16 GEMM passed numerically
// (0.0078) but D1_gemm ~137us > scalar D1 ~100us — the SIXTH structurally
// different D1 implementation to converge at ~100-140us against ~25us
// models (occupancy x3, atomics, transpose, readlane, MFMA-GEMM). No
// further falsifiable theory at this granularity; D1's counters have never
// been visible (below top-5 cutoff). Reverting to the best configuration:
//   D1 k_offset_all (r19: 256 blk x 1024 thr, 16 waves x 20ch, no atomics)
//      + XCD swizzle (b&7=XCD owns a 32-row strip of one batch) so the
//      3-row halo windows share a per-XCD L2 instead of being re-fetched
//      3x across XCDs (~5-10us mechanism, ~0 risk: bijective remap only).
//   D2 k_fused_gemm byte-identical to r19/r20/r22 (proven, 121-135us).
// Predict total 225-236; if >=240 it's machine noise and r19's config is
// the session floor (both kernels exhausted at this abstraction level).

typedef __bf16 bf16x8 __attribute__((ext_vector_type(8)));
typedef float f32x4 __attribute__((ext_vector_type(4)));
typedef float float2_u __attribute__((ext_vector_type(2), aligned(4)));

__device__ __forceinline__ unsigned short f2bf(float f) {
  unsigned b = __float_as_uint(f);
  return (unsigned short)((b + 0x7fffu + ((b >> 16) & 1u)) >> 16);
}

// ---------------------------------------------------------------------------
// D1: weight prep (K0) + offset conv (K1, full-channel, no atomics).
// 256 blocks x 1024 thr; block -> (n,ho) via XCD swizzle; 16 waves x 20 ch.
// ---------------------------------------------------------------------------
__global__ __launch_bounds__(1024) void k_offset_all(
    const float* __restrict__ x, const float* __restrict__ depth,
    const float* __restrict__ w, const float* __restrict__ off_w,
    const float* __restrict__ off_b,
    unsigned short* __restrict__ wbf, float* __restrict__ offs)
{
  const int tid = threadIdx.x;
  // --- K0: weight fp32 -> bf16, grid-stride (589824 / 262144 thr)
  for (int i = blockIdx.x * 1024 + tid; i < 589824; i += 262144)
    wbf[i] = f2bf(w[i]);

  // XCD swizzle (same shape as fused): b&7 = XCD; each XCD owns a 32-row
  // strip of one batch -> halo rows (ho-1,ho,ho+1) L2-resident per XCD.
  const int b    = blockIdx.x;
  const int xcd  = b & 7, bslot = b >> 3;   // bslot 0..31
  const int n    = xcd >> 1;
  const int ho   = ((xcd & 1) << 5) + bslot;
  const int lane = tid & 63;              // == wo
  const int wave = tid >> 6;              // 0..15

  float acc[18];
#pragma unroll
  for (int i = 0; i < 18; ++i) acc[i] = 0.f;

  const int c0 = __builtin_amdgcn_readfirstlane(wave * 20);

  for (int ci = 0; ci < 20; ++ci) {
    const int c = c0 + ci;
    const float* p = (c < 256) ? (x + (((n << 8) + c) << 12))
                               : (depth + (((n << 6) + (c - 256)) << 12));
    const float v0 = (ho > 0)  ? p[((ho - 1) << 6) + lane] : 0.f;
    const float v1 =             p[( ho      << 6) + lane];
    const float v2 = (ho < 63) ? p[((ho + 1) << 6) + lane] : 0.f;

    float v[9];
#pragma unroll
    for (int ky = 0; ky < 3; ++ky) {
      const float r = (ky == 0) ? v0 : ((ky == 1) ? v1 : v2);
#pragma unroll
      for (int kx = 0; kx < 3; ++kx) {
        const int src = lane + kx - 1;
        const float s = __shfl(r, src & 63);
        v[ky * 3 + kx] = (src >= 0 && src < 64) ? s : 0.f;
      }
    }
    const float* wp = off_w + c * 9;   // wave-uniform address
#pragma unroll
    for (int co = 0; co < 18; ++co) {
      const float* ww = wp + co * 2880;
#pragma unroll
      for (int t = 0; t < 9; ++t) acc[co] += v[t] * ww[t];
    }
  }

  __shared__ float red[16][18][64];       // 73728 B
#pragma unroll
  for (int co = 0; co < 18; ++co) red[wave][co][lane] = acc[co];
  __syncthreads();
  for (int o = tid; o < 18 * 64; o += 1024) {
    const int co = o >> 6, wo = o & 63;
    float s = off_b[co];
#pragma unroll
    for (int wv = 0; wv < 16; ++wv) s += red[wv][co][wo];
    offs[((n * 18 + co) << 12) + (ho << 6) + wo] = s;   // direct store
  }
}

// ---------------------------------------------------------------------------
// D2: fused mask deform conv (K2) + main modulated deform conv GEMM (K3).
// Block = (n,ho) via XCD swizzle, 512 thr = 8 waves, grid 256. (= r19/r20/r22)
// LDS pool layout (101376 B):
//   [0      .. 78336) strip   9 x 8704
//   [78336  .. 87552) Bs      64 x 72 u16     \
//   [87552  .. 96768) pwT     9 x 64 float4    > aliased by red[8][9][64]
//   [96768  .. 99072) piT     9 x 64 int      /  (18432 B, phase-M only)
//   [99072  ..101376) mskL    9 x 64 float
// ---------------------------------------------------------------------------
__device__ __forceinline__ void stage_channel_row(const float* src, char* dstb,
                                                  int lane) {
  // 32 rows x 256B; each size-4 call writes one row (64 lanes x 4B, linear).
  const char* s = (const char*)src + lane * 4;
#pragma unroll
  for (int j = 0; j < 32; ++j)
    __builtin_amdgcn_global_load_lds(
        (const __attribute__((address_space(1))) void*)(s + j * 256),
        (__attribute__((address_space(3))) void*)(dstb + j * 272), 4, 0, 0);
}

__global__ __launch_bounds__(512, 2) void k_fused_gemm(
    const float* __restrict__ x, const float* __restrict__ depth,
    const float* __restrict__ offs, const float* __restrict__ mask_w,
    const float* __restrict__ mask_b, const unsigned short* __restrict__ wbf,
    const float* __restrict__ bias, float* __restrict__ out)
{
  __shared__ __align__(16) char pool[101376];
  char* stripc = pool;
  unsigned short (*Bs)[72]  = (unsigned short (*)[72])(pool + 78336);
  float4 (*pwT)[64]         = (float4 (*)[64])(pool + 87552);
  int (*piT)[64]            = (int (*)[64])(pool + 96768);
  float (*mskL)[64]         = (float (*)[64])(pool + 99072);
  float (*red)[9][64]       = (float (*)[9][64])(pool + 78336);  // phase-M alias

  const int tid = threadIdx.x;
  // XCD swizzle: b&7 = XCD; each XCD owns a 32-row strip of one batch.
  const int b    = blockIdx.x;            // 256 blocks
  const int xcd  = b & 7, bslot = b >> 3; // bslot 0..31
  const int n    = xcd >> 1;
  const int ho   = ((xcd & 1) << 5) + bslot;      // 0..63
  const int pxb  = ho << 6;                       // px base within batch
  const int ylo  = min(max(ho - 15, 0), 32);      // strip rows [ylo, ylo+32)

  const int pxl  = tid & 63;        // px within row (= lane)
  const int oct  = tid >> 6;        // wave id; k-octet of 8
  const int lane = tid & 63;
  const int mrow = lane & 15;
  const int koct = lane >> 4;       // 0..3 -> k-subgroup of 8
  const float* xn = x + ((long)(n << 8) << 12);

  // --- prologue: stage channels 0..7 (window of iter 0), one per wave.
  stage_channel_row(xn + (oct << 12) + (ylo << 6), stripc + oct * 8704, lane);
  int c_staged = 8;

  // =============== Phase M: mask deform conv for this (n,ho) row ===========
  {
    const int wo = lane;
    int ia[9], ib[9];
    float w0[9], w1[9], w2c[9], w3[9];
    const float* op = offs + ((n * 18) << 12) + (ho << 6) + wo;
#pragma unroll
    for (int k = 0; k < 9; ++k) {
      const float dy = op[(2 * k) << 12];
      const float dx = op[(2 * k + 1) << 12];
      const float yy = (float)(ho - 1 + k / 3) + dy;
      const float xx = (float)(wo - 1 + k % 3) + dx;
      const float y0f = floorf(yy), x0f = floorf(xx);
      const float ly = yy - y0f, lx = xx - x0f;
      const int y0 = (int)y0f, x0 = (int)x0f;
      const int y0c = min(max(y0, 0), 63);
      const int y1c = min(max(y0 + 1, 0), 63);
      const float fy0 = (y0 >= 0 && y0 < 64) ? 1.f : 0.f;
      const float fy1 = (y0 >= -1 && y0 < 63) ? 1.f : 0.f;
      const int x0c = min(max(x0, 0), 63);
      const int x1c = min(max(x0 + 1, 0), 63);
      const int bx  = min(max(x0, 0), 62);
      const float vx0 = (x0 >= 0 && x0 < 64) ? 1.f : 0.f;
      const float vx1 = (x0 >= -1 && x0 < 63) ? 1.f : 0.f;
      const float wl = (1.f - lx) * vx0 * ((x0c == bx) ? 1.f : 0.f)
                     + lx * vx1 * ((x1c == bx) ? 1.f : 0.f);
      const float wr = (1.f - lx) * vx0 * ((x0c == bx + 1) ? 1.f : 0.f)
                     + lx * vx1 * ((x1c == bx + 1) ? 1.f : 0.f);
      const float a0 = (1.f - ly) * fy0;
      const float a1 = ly * fy1;
      ia[k] = ((y0c << 6) + bx) << 2;
      ib[k] = ((y1c << 6) + bx) << 2;
      w0[k] = wl * a0;  w1[k] = wr * a0;
      w2c[k] = wl * a1; w3[k] = wr * a1;
    }

    float acc2[9];
#pragma unroll
    for (int i = 0; i < 9; ++i) acc2[i] = 0.f;

    const int cbase = __builtin_amdgcn_readfirstlane(oct * 8);
    for (int cc = 0; cc < 8; ++cc) {
      const int c = cbase + cc;
      const char* p = (const char*)(depth + (((n << 6) + c) << 12));
      float val[9];
#pragma unroll
      for (int k = 0; k < 9; ++k) {
        const float2_u A = *(const float2_u*)(p + ia[k]);
        const float2_u B = *(const float2_u*)(p + ib[k]);
        val[k] = A.x * w0[k] + A.y * w1[k] + B.x * w2c[k] + B.y * w3[k];
      }
      const float* wp = mask_w + c * 9;
#pragma unroll
      for (int co = 0; co < 9; ++co) {
#pragma unroll
        for (int k = 0; k < 9; ++k) acc2[co] += val[k] * wp[co * 576 + k];
      }
    }
#pragma unroll
    for (int co = 0; co < 9; ++co) red[oct][co][lane] = acc2[co];
  }
  __syncthreads();   // red complete (also drains prologue staging vmcnt)

  for (int o = tid; o < 576; o += 512) {
    const int co = o >> 6, wo = o & 63;
    float s = mask_b[co];
#pragma unroll
    for (int wv = 0; wv < 8; ++wv) s += red[wv][co][wo];
    mskL[co][wo] = 1.f / (1.f + expf(-s));
  }
  __syncthreads();   // mskL ready; red dead -> Bs/pwT/piT region free

  // =============== Phase P: sampling params into LDS tables ================
  for (int e = tid; e < 576; e += 512) {
    const int tap = e >> 6, pl = e & 63;
    const int wo = pl;
    const float dy = offs[((n * 18 + 2 * tap) << 12) + pxb + pl];
    const float dx = offs[((n * 18 + 2 * tap + 1) << 12) + pxb + pl];
    const float m  = mskL[tap][pl];
    const float yy = (float)(ho - 1 + tap / 3) + dy;
    const float xx = (float)(wo - 1 + tap % 3) + dx;
    const float y0f = floorf(yy), x0f = floorf(xx);
    const float ly = yy - y0f, lx = xx - x0f;
    const int y0 = (int)y0f, x0 = (int)x0f;
    const int y0c = min(max(y0, 0), 63);
    const int y1c = min(max(y0 + 1, 0), 63);
    const float fy0 = (y0 >= 0 && y0 < 64) ? 1.f : 0.f;
    const float fy1 = (y0 >= -1 && y0 < 63) ? 1.f : 0.f;
    const int x0c = min(max(x0, 0), 63);
    const int x1c = min(max(x0 + 1, 0), 63);
    const int bx  = min(max(x0, 0), 62);
    const float vx0 = (x0 >= 0 && x0 < 64) ? 1.f : 0.f;
    const float vx1 = (x0 >= -1 && x0 < 63) ? 1.f : 0.f;
    const float wl = (1.f - lx) * vx0 * ((x0c == bx) ? 1.f : 0.f)
                   + lx * vx1 * ((x1c == bx) ? 1.f : 0.f);
    const float wr = (1.f - lx) * vx0 * ((x0c == bx + 1) ? 1.f : 0.f)
                   + lx * vx1 * ((x1c == bx + 1) ? 1.f : 0.f);
    const float a0 = (1.f - ly) * fy0 * m;
    const float a1 = ly * fy1 * m;
    pwT[tap][pl] = make_float4(wl * a0, wr * a0, wl * a1, wr * a1);
    // strip-relative byte addrs (row stride 272B) + bad flag
    const int ry0 = y0c - ylo, ry1 = y1c - ylo;
    const int ry0c = min(max(ry0, 0), 31), ry1c = min(max(ry1, 0), 31);
    const int bad = ((ry0 != ry0c) || (ry1 != ry1c)) ? 1 : 0;
    const int ad0 = ry0c * 272 + (bx << 2);      // <= 8680 < 16384
    const int ad1 = ry1c * 272 + (bx << 2);
    piT[tap][pl] = ad0 | (ad1 << 14) | (bad << 28);
  }
  __syncthreads();   // params + prologue strip visible

  // --- gather: one k-octet (8 k) per lane into Bs; params from LDS tables.
  auto gather = [&](int ic) {
    const int k0 = (ic << 6) + (oct << 3);
    const int c0 = (int)(((unsigned)k0 * 7282u) >> 16);    // k0/9
    int tap = k0 - 9 * c0;
    const int s9 = (int)(((unsigned)c0 * 7282u) >> 16);    // c0/9
    int soff = (c0 - 9 * s9) * 8704;                       // slot byte offset

    __align__(16) unsigned short v[8];
    unsigned badm = 0;
#pragma unroll
    for (int j = 0; j < 8; ++j) {
      const int pk  = piT[tap][pxl];              // ds_read_b32
      const float4 w = pwT[tap][pxl];             // ds_read_b128
      const float2_u A = *(const float2_u*)(stripc + soff + (pk & 16383));
      const float2_u B = *(const float2_u*)(stripc + soff + ((pk >> 14) & 16383));
      v[j] = f2bf(A.x * w.x + A.y * w.y + B.x * w.z + B.y * w.w);
      badm |= ((unsigned)pk >> 28) << j;          // bit28 = bad
      if (++tap == 9) {
        tap = 0;
        soff += 8704; if (soff == 9 * 8704) soff = 0;
      }
    }

    if (__builtin_expect(badm != 0, 0)) {         // ~10 events per launch
#pragma unroll
      for (int j = 0; j < 8; ++j) if (badm & (1u << j)) {
        const int k = k0 + j;
        const int c = (int)(((unsigned)k * 7282u) >> 16);
        const int tp = k - 9 * c;
        // full recompute from global (identical math to phase P)
        const float dy = offs[((n * 18 + 2 * tp) << 12) + pxb + pxl];
        const float dx = offs[((n * 18 + 2 * tp + 1) << 12) + pxb + pxl];
        const float m  = mskL[tp][pxl];
        const float yy = (float)(ho - 1 + tp / 3) + dy;
        const float xx = (float)(pxl - 1 + tp % 3) + dx;
        const float y0f = floorf(yy), x0f = floorf(xx);
        const float ly = yy - y0f, lx = xx - x0f;
        const int y0 = (int)y0f, x0 = (int)x0f;
        const int y0c = min(max(y0, 0), 63);
        const int y1c = min(max(y0 + 1, 0), 63);
        const float fy0 = (y0 >= 0 && y0 < 64) ? 1.f : 0.f;
        const float fy1 = (y0 >= -1 && y0 < 63) ? 1.f : 0.f;
        const int x0c = min(max(x0, 0), 63);
        const int x1c = min(max(x0 + 1, 0), 63);
        const int bx  = min(max(x0, 0), 62);
        const float vx0 = (x0 >= 0 && x0 < 64) ? 1.f : 0.f;
        const float vx1 = (x0 >= -1 && x0 < 63) ? 1.f : 0.f;
        const float wl = (1.f - lx) * vx0 * ((x0c == bx) ? 1.f : 0.f)
                       + lx * vx1 * ((x1c == bx) ? 1.f : 0.f);
        const float wr = (1.f - lx) * vx0 * ((x0c == bx + 1) ? 1.f : 0.f)
                       + lx * vx1 * ((x1c == bx + 1) ? 1.f : 0.f);
        const float a0 = (1.f - ly) * fy0 * m;
        const float a1 = ly * fy1 * m;
        const char* pg = (const char*)xn + ((long)c << 14);
        const float2_u Ag = *(const float2_u*)(pg + (((y0c << 6) + bx) << 2));
        const float2_u Bg = *(const float2_u*)(pg + (((y1c << 6) + bx) << 2));
        v[j] = f2bf(Ag.x * (wl * a0) + Ag.y * (wr * a0) +
                    Bg.x * (wl * a1) + Bg.y * (wr * a1));
      }
    }
    *(int4*)&Bs[pxl][oct << 3] = *(const int4*)v;
  };

  // A-fragment prefetch registers for iter 0
  bf16x8 afc[2][2];
#pragma unroll
  for (int mt = 0; mt < 2; ++mt)
#pragma unroll
    for (int ks = 0; ks < 2; ++ks) {
      const int row = (oct << 5) + (mt << 4) + mrow;
      const int col = (ks << 5) + (koct << 3);
      afc[mt][ks] = *(const bf16x8*)(wbf + row * 2304 + col);
    }

  gather(0);
  __syncthreads();

  f32x4 acc[2][4];
#pragma unroll
  for (int mt = 0; mt < 2; ++mt)
#pragma unroll
    for (int nt = 0; nt < 4; ++nt)
#pragma unroll
      for (int r = 0; r < 4; ++r) acc[mt][nt][r] = 0.f;

  for (int ic = 0; ic < 36; ++ic) {
    // stage next window (overlaps MFMA; drained at barrier) + af prefetch
    if (ic < 35) {
      const int c_end = (64 * ic + 127) / 9;          // c_hi(ic+1) <= 255
      const int cw = c_staged + oct;
      if (cw <= c_end) {
        const int slt = cw - 9 * (int)(((unsigned)cw * 7282u) >> 16);
        stage_channel_row(xn + (cw << 12) + (ylo << 6),
                          stripc + slt * 8704, lane);
      }
      c_staged = c_end + 1;
    }

    bf16x8 afn[2][2];
    if (ic < 35) {
      const int kc = (ic + 1) << 6;
#pragma unroll
      for (int mt = 0; mt < 2; ++mt)
#pragma unroll
        for (int ks = 0; ks < 2; ++ks) {
          const int row = (oct << 5) + (mt << 4) + mrow;
          const int col = kc + (ks << 5) + (koct << 3);
          afn[mt][ks] = *(const bf16x8*)(wbf + row * 2304 + col);
        }
    }

#pragma unroll
    for (int ks = 0; ks < 2; ++ks)
#pragma unroll
      for (int nt = 0; nt < 4; ++nt) {
        const bf16x8 bfr =
            *(const bf16x8*)&Bs[(nt << 4) + mrow][(ks << 5) + (koct << 3)];
        acc[0][nt] = __builtin_amdgcn_mfma_f32_16x16x32_bf16(afc[0][ks], bfr,
                                                             acc[0][nt], 0, 0, 0);
        acc[1][nt] = __builtin_amdgcn_mfma_f32_16x16x32_bf16(afc[1][ks], bfr,
                                                             acc[1][nt], 0, 0, 0);
      }

    __syncthreads();           // drains stage; Bs free for rewrite
    if (ic < 35) gather(ic + 1);
    __syncthreads();           // Bs ready for next MFMA; strip safe to restage

#pragma unroll
    for (int mt = 0; mt < 2; ++mt)
#pragma unroll
      for (int ks = 0; ks < 2; ++ks) afc[mt][ks] = afn[mt][ks];
  }

  // epilogue: C/D layout col=lane&15 (px), row=(lane>>4)*4+r (co)
#pragma unroll
  for (int mt = 0; mt < 2; ++mt)
#pragma unroll
    for (int nt = 0; nt < 4; ++nt)
#pragma unroll
      for (int r = 0; r < 4; ++r) {
        const int co = (oct << 5) + (mt << 4) + ((lane >> 4) << 2) + r;
        const int pxg = pxb + (nt << 4) + (lane & 15);
        out[(((n << 8) + co) << 12) + pxg] = acc[mt][nt][r] + bias[co];
      }
}

// ---------------------------------------------------------------------------
extern "C" void kernel_launch(void* const* d_in, const int* in_sizes, int n_in,
                              void* d_out, int out_size, void* d_ws, size_t ws_size,
                              hipStream_t stream) {
  const float* x      = (const float*)d_in[0];
  const float* depth  = (const float*)d_in[1];
  const float* weight = (const float*)d_in[2];
  const float* bias   = (const float*)d_in[3];
  const float* off_w  = (const float*)d_in[4];
  const float* off_b  = (const float*)d_in[5];
  const float* mask_w = (const float*)d_in[6];
  const float* mask_b = (const float*)d_in[7];
  float* out = (float*)d_out;

  float* offs = (float*)d_ws;                              // 294912 f
  unsigned short* wbf = (unsigned short*)(offs + 294912);  // 589824 u16

  k_offset_all<<<256, 1024, 0, stream>>>(x, depth, weight, off_w, off_b,
                                         wbf, offs);
  k_fused_gemm<<<256, 512, 0, stream>>>(x, depth, offs, mask_w, mask_b,
                                        wbf, bias, out);
}